// Round 1
// baseline (579.760 us; speedup 1.0000x reference)
//
#include <hip/hip_runtime.h>
#include <hip/hip_bf16.h>
#include <cstddef>

#define B_  8
#define S_  32
#define BT_ 256      // B*S
#define N_  2000
#define E_  64000
#define GH_ 32
#define H_  64
#define G4_ 256      // 4*H
#define D_  64000    // N*GH
#define NEG_SLOPE_ 0.2f

#define TN_NODES 20  // nodes per K-chunk in the big matmul (2000/20 = 100 chunks)

__device__ __forceinline__ float fsigmoid(float x) { return 1.0f / (1.0f + __expf(-x)); }
__device__ __forceinline__ float ftanh_(float x)   { return 1.0f - 2.0f / (__expf(2.0f * x) + 1.0f); }

// ---------------------------------------------------------------------------
// Kernel 1: GAT aggregation. One block per (b,s). Single pass over edges:
// agg[n] = sum_in exp(e)*x[src] / sum_in exp(e)   (max-subtraction is a no-op)
// Writes agg transposed: agg_T[n*256 + bt] for coalesced reads in the matmul.
// ---------------------------------------------------------------------------
__global__ __launch_bounds__(256) void gat_agg_kernel(
    const float* __restrict__ x, const int* __restrict__ ei,
    const float* __restrict__ w_lin, const float* __restrict__ att_src,
    const float* __restrict__ att_dst, float* __restrict__ agg_T)
{
  const int bt  = blockIdx.x;
  const int tid = threadIdx.x;
  __shared__ float xs[N_];
  __shared__ float num[N_];
  __shared__ float den[N_];

  // c_s = dot(w_lin, att_src), c_d = dot(w_lin, att_dst) — uniform, scalar loads
  float c_s = 0.f, c_d = 0.f;
  for (int g = 0; g < GH_; ++g) {
    float w = w_lin[g];
    c_s += w * att_src[g];
    c_d += w * att_dst[g];
  }

  for (int n = tid; n < N_; n += 256) {
    xs[n]  = x[(size_t)bt * N_ + n];
    num[n] = 0.f;
    den[n] = 0.f;
  }
  __syncthreads();

  // random edges
  for (int i = tid; i < E_; i += 256) {
    const int s = ei[i];
    const int d = ei[E_ + i];
    const float xsv = xs[s];
    float e = c_s * xsv + c_d * xs[d];
    e = e > 0.f ? e : NEG_SLOPE_ * e;
    const float w = __expf(e);
    atomicAdd(&den[d], w);
    atomicAdd(&num[d], w * xsv);
  }
  // self loops (appended for every node, PyG default)
  for (int n = tid; n < N_; n += 256) {
    const float xv = xs[n];
    float e = (c_s + c_d) * xv;
    e = e > 0.f ? e : NEG_SLOPE_ * e;
    const float w = __expf(e);
    atomicAdd(&den[n], w);
    atomicAdd(&num[n], w * xv);
  }
  __syncthreads();

  for (int n = tid; n < N_; n += 256) {
    agg_T[(size_t)n * BT_ + bt] = num[n] / den[n];
  }
}

// ---------------------------------------------------------------------------
// Kernel 2: pre_gates[bt, j] += sum_{n,gh} W_ih[j, n*32+gh] *
//                               relu(agg[bt,n]*w_lin[gh] + gat_bias[gh])
// fp32 VALU matmul, 128x128 tile, 8x8 microtile, K split into 100 chunks,
// accumulated with global fp32 atomicAdd. lstm_in generated on the fly.
// grid = (2 bt-tiles, 2 j-tiles, 100 chunks), block = 256.
// ---------------------------------------------------------------------------
__global__ __launch_bounds__(256) void gate_matmul_kernel(
    const float* __restrict__ W_ih, const float* __restrict__ agg_T,
    const float* __restrict__ w_lin, const float* __restrict__ gat_bias,
    float* __restrict__ pre_gates)
{
  __shared__ __align__(16) float As[GH_ * 128];  // [gh][bt]
  __shared__ __align__(16) float Bs[GH_ * 128];  // [gh][j]
  __shared__ float wl_s[GH_];
  __shared__ float gb_s[GH_];

  const int tid = threadIdx.x;
  const int bt0 = blockIdx.x * 128;
  const int j0  = blockIdx.y * 128;
  const int n0  = blockIdx.z * TN_NODES;

  if (tid < GH_) { wl_s[tid] = w_lin[tid]; gb_s[tid] = gat_bias[tid]; }

  const int tx = tid & 15;   // j group: j = tx*4..+3 and 64+tx*4..+3
  const int ty = tid >> 4;   // bt group: bt = ty*8..+7

  float acc[8][8];
#pragma unroll
  for (int i = 0; i < 8; ++i)
#pragma unroll
    for (int j = 0; j < 8; ++j) acc[i][j] = 0.f;

  __syncthreads();

  const int r  = tid >> 3;         // 0..31 (row within pass for B staging)
  const int cc = (tid & 7) * 4;    // 0,4,...,28
  const int btl = tid & 127;
  const int gh0 = (tid >> 7) * 16; // 0 or 16

  for (int nn = 0; nn < TN_NODES; ++nn) {
    const int n = n0 + nn;

    // stage B: W_ih rows j0..j0+127, cols n*32..n*32+31  -> Bs[gh][j]
#pragma unroll
    for (int p = 0; p < 4; ++p) {
      const int jr = r + p * 32;
      const float4 v = *(const float4*)(W_ih + (size_t)(j0 + jr) * D_ + (size_t)n * GH_ + cc);
      Bs[(cc + 0) * 128 + jr] = v.x;
      Bs[(cc + 1) * 128 + jr] = v.y;
      Bs[(cc + 2) * 128 + jr] = v.z;
      Bs[(cc + 3) * 128 + jr] = v.w;
    }

    // stage A: relu expansion of agg -> As[gh][bt]
    {
      const float a = agg_T[(size_t)n * BT_ + bt0 + btl];
#pragma unroll
      for (int g = 0; g < 16; ++g) {
        const int gh = gh0 + g;
        float rv = fmaf(a, wl_s[gh], gb_s[gh]);
        As[gh * 128 + btl] = rv > 0.f ? rv : 0.f;
      }
    }
    __syncthreads();

#pragma unroll 4
    for (int k = 0; k < GH_; ++k) {
      float av[8], bv[8];
      *(float4*)&av[0] = *(const float4*)&As[k * 128 + ty * 8];
      *(float4*)&av[4] = *(const float4*)&As[k * 128 + ty * 8 + 4];
      *(float4*)&bv[0] = *(const float4*)&Bs[k * 128 + tx * 4];
      *(float4*)&bv[4] = *(const float4*)&Bs[k * 128 + 64 + tx * 4];
#pragma unroll
      for (int i = 0; i < 8; ++i)
#pragma unroll
        for (int j = 0; j < 8; ++j)
          acc[i][j] = fmaf(av[i], bv[j], acc[i][j]);
    }
    __syncthreads();
  }

  // accumulate into pre_gates
#pragma unroll
  for (int i = 0; i < 8; ++i) {
    const int bt = bt0 + ty * 8 + i;
#pragma unroll
    for (int jj = 0; jj < 8; ++jj) {
      const int j = j0 + ((jj < 4) ? (tx * 4 + jj) : (64 + tx * 4 + (jj - 4)));
      atomicAdd(&pre_gates[bt * G4_ + j], acc[i][jj]);
    }
  }
}

// ---------------------------------------------------------------------------
// Kernel 3: LSTM recurrence over t=0..31. One block per batch b.
// W_hh staged in LDS with stride 65 (conflict-free). c kept in registers.
// Gate order (PyTorch/ref): [i; f; g; o] chunks of 64.
// ---------------------------------------------------------------------------
__global__ __launch_bounds__(256) void lstm_kernel(
    const float* __restrict__ pre_gates, const float* __restrict__ W_hh,
    const float* __restrict__ b_ih, const float* __restrict__ b_hh,
    float* __restrict__ hT)
{
  const int b   = blockIdx.x;
  const int tid = threadIdx.x;
  __shared__ float Whh_s[G4_ * 65];
  __shared__ float h_s[H_];
  __shared__ float g_s[G4_];

  for (int idx = tid; idx < G4_ * H_; idx += 256) {
    const int j = idx >> 6;
    const int k = idx & 63;
    Whh_s[j * 65 + k] = W_hh[idx];
  }
  if (tid < H_) h_s[tid] = 0.f;
  float c = 0.f;
  const float bias = b_ih[tid] + b_hh[tid];
  __syncthreads();

  for (int t = 0; t < S_; ++t) {
    float g = pre_gates[(size_t)(b * S_ + t) * G4_ + tid] + bias;
#pragma unroll
    for (int k = 0; k < H_; ++k) g = fmaf(Whh_s[tid * 65 + k], h_s[k], g);
    g_s[tid] = g;
    __syncthreads();
    if (tid < H_) {
      const float ig = fsigmoid(g_s[tid]);
      const float fg = fsigmoid(g_s[H_ + tid]);
      const float gg = ftanh_(g_s[2 * H_ + tid]);
      const float og = fsigmoid(g_s[3 * H_ + tid]);
      c = fg * c + ig * gg;
      h_s[tid] = og * ftanh_(c);
    }
    __syncthreads();
  }
  if (tid < H_) hT[b * H_ + tid] = h_s[tid];
}

// ---------------------------------------------------------------------------
// Kernel 4: head. out[b,n] = b_head[n] + sum_h hT[b,h]*W_head[n,h]
// ---------------------------------------------------------------------------
__global__ __launch_bounds__(256) void head_kernel(
    const float* __restrict__ hT, const float* __restrict__ W_head,
    const float* __restrict__ b_head, float* __restrict__ out)
{
  const int o = blockIdx.x * 256 + threadIdx.x;
  if (o >= B_ * N_) return;
  const int b = o / N_;
  const int n = o - b * N_;
  const float4* w4 = (const float4*)(W_head + (size_t)n * H_);
  const float4* h4 = (const float4*)(hT + (size_t)b * H_);
  float acc = b_head[n];
#pragma unroll
  for (int q = 0; q < H_ / 4; ++q) {
    const float4 w = w4[q];
    const float4 h = h4[q];
    acc += w.x * h.x + w.y * h.y + w.z * h.z + w.w * h.w;
  }
  out[o] = acc;
}

// ---------------------------------------------------------------------------
extern "C" void kernel_launch(void* const* d_in, const int* in_sizes, int n_in,
                              void* d_out, int out_size, void* d_ws, size_t ws_size,
                              hipStream_t stream) {
  const float* x        = (const float*)d_in[0];
  const int*   ei       = (const int*)  d_in[1];
  const float* w_lin    = (const float*)d_in[2];
  const float* att_src  = (const float*)d_in[3];
  const float* att_dst  = (const float*)d_in[4];
  const float* gat_bias = (const float*)d_in[5];
  const float* W_ih     = (const float*)d_in[6];
  const float* W_hh     = (const float*)d_in[7];
  const float* b_ih     = (const float*)d_in[8];
  const float* b_hh     = (const float*)d_in[9];
  const float* W_head   = (const float*)d_in[10];
  const float* b_head   = (const float*)d_in[11];
  float* out = (float*)d_out;

  char* ws = (char*)d_ws;
  float* agg_T     = (float*)ws;                         // 2000*256*4 = 2,048,000 B
  float* pre_gates = (float*)(ws + 2048000);             // 256*256*4  =   262,144 B
  float* hT        = (float*)(ws + 2048000 + 262144);    // 8*64*4     =     2,048 B

  hipMemsetAsync(pre_gates, 0, G4_ * BT_ * sizeof(float), stream);

  gat_agg_kernel<<<dim3(BT_), dim3(256), 0, stream>>>(x, ei, w_lin, att_src, att_dst, agg_T);

  gate_matmul_kernel<<<dim3(2, 2, N_ / TN_NODES), dim3(256), 0, stream>>>(
      W_ih, agg_T, w_lin, gat_bias, pre_gates);

  lstm_kernel<<<dim3(B_), dim3(256), 0, stream>>>(pre_gates, W_hh, b_ih, b_hh, hT);

  head_kernel<<<dim3((B_ * N_ + 255) / 256), dim3(256), 0, stream>>>(hT, W_head, b_head, out);
}

// Round 2
// 395.305 us; speedup vs baseline: 1.4666x; 1.4666x over previous
//
#include <hip/hip_runtime.h>
#include <hip/hip_bf16.h>
#include <cstddef>
#include <cstdint>

#define B_  8
#define S_  32
#define BT_ 256      // B*S
#define N_  2000
#define E_  64000
#define GH_ 32
#define H_  64
#define G4_ 256      // 4*H
#define D_  64000    // N*GH
#define NEG_SLOPE_ 0.2f

#define KC_   125    // K-chunks
#define NPC_  16     // nodes per chunk (125*16 = 2000)

typedef __attribute__((ext_vector_type(8))) short short8;
typedef __attribute__((ext_vector_type(4))) float floatx4;
union U8 { uint32_t u[4]; short8 s; };

__device__ __forceinline__ float fsigmoid(float x) { return 1.0f / (1.0f + __expf(-x)); }
__device__ __forceinline__ float ftanh_(float x)   { return 1.0f - 2.0f / (__expf(2.0f * x) + 1.0f); }

// split two fp32 into packed bf16-hi pair and bf16-lo pair (bit-truncation;
// lo = v - hi is exact, lo's own truncation is ~2^-16 relative to v)
__device__ __forceinline__ void split2(float v0, float v1, uint32_t& hi, uint32_t& lo) {
  uint32_t b0 = __float_as_uint(v0), b1 = __float_as_uint(v1);
  uint32_t h0 = b0 & 0xffff0000u,    h1 = b1 & 0xffff0000u;
  hi = (b0 >> 16) | h1;
  float l0 = v0 - __uint_as_float(h0);
  float l1 = v1 - __uint_as_float(h1);
  lo = (__float_as_uint(l0) >> 16) | (__float_as_uint(l1) & 0xffff0000u);
}

// ---------------------------------------------------------------------------
// Kernel 1: GAT aggregation. One block per (b,s). Single pass over edges:
// agg[n] = sum_in exp(e)*x[src] / sum_in exp(e)   (max-subtraction is a no-op)
// Writes agg transposed: agg_T[n*256 + bt].
// ---------------------------------------------------------------------------
__global__ __launch_bounds__(256) void gat_agg_kernel(
    const float* __restrict__ x, const int* __restrict__ ei,
    const float* __restrict__ w_lin, const float* __restrict__ att_src,
    const float* __restrict__ att_dst, float* __restrict__ agg_T)
{
  const int bt  = blockIdx.x;
  const int tid = threadIdx.x;
  __shared__ float xs[N_];
  __shared__ float num[N_];
  __shared__ float den[N_];

  float c_s = 0.f, c_d = 0.f;
  for (int g = 0; g < GH_; ++g) {
    float w = w_lin[g];
    c_s += w * att_src[g];
    c_d += w * att_dst[g];
  }

  for (int n = tid; n < N_; n += 256) {
    xs[n]  = x[(size_t)bt * N_ + n];
    num[n] = 0.f;
    den[n] = 0.f;
  }
  __syncthreads();

  for (int i = tid; i < E_; i += 256) {
    const int s = ei[i];
    const int d = ei[E_ + i];
    const float xsv = xs[s];
    float e = c_s * xsv + c_d * xs[d];
    e = e > 0.f ? e : NEG_SLOPE_ * e;
    const float w = __expf(e);
    atomicAdd(&den[d], w);
    atomicAdd(&num[d], w * xsv);
  }
  for (int n = tid; n < N_; n += 256) {
    const float xv = xs[n];
    float e = (c_s + c_d) * xv;
    e = e > 0.f ? e : NEG_SLOPE_ * e;
    const float w = __expf(e);
    atomicAdd(&den[n], w);
    atomicAdd(&num[n], w * xv);
  }
  __syncthreads();

  for (int n = tid; n < N_; n += 256) {
    agg_T[(size_t)n * BT_ + bt] = num[n] / den[n];
  }
}

// ---------------------------------------------------------------------------
// Kernel 2: split-bf16 MFMA matmul.
// pre_gates[bt, j] = sum_{n,gh} W_ih[j, n*32+gh] * relu(agg[bt,n]*w_lin[gh]+gat_bias[gh])
// Block tile: M=256 (all bt) x N=64 (one j-quarter); 4 waves each own N=16.
// K-chunked: 16 nodes (512 K) per block; grid = (4 N-blocks, 125 chunks).
// B (W_ih) loaded fp32 straight to registers (each line read exactly once),
// bit-split into bf16 hi/lo. A expanded on the fly from agg (rank-1 + relu).
// 3 MFMA passes: Ah*Bh + Al*Bh + Ah*Bl (drop Al*Bl, ~2^-16 relative).
// No barriers in the K loop; no atomics (private fp32 partial per chunk).
// ---------------------------------------------------------------------------
__global__ __launch_bounds__(256) void gate_mfma_kernel(
    const float* __restrict__ W_ih, const float* __restrict__ agg_T,
    const float* __restrict__ w_lin, const float* __restrict__ gat_bias,
    float* __restrict__ partial, float* __restrict__ pre_gates, int use_atomic)
{
  __shared__ float agg_s[NPC_ * 256];

  const int tid  = threadIdx.x;
  const int nb   = blockIdx.x;     // 0..3  (N-block of 64 gates)
  const int kc   = blockIdx.y;     // 0..124 (K-chunk of 16 nodes)
  const int n0   = kc * NPC_;
  const int wv   = tid >> 6;
  const int lane = tid & 63;
  const int i16  = lane & 15;      // A: m-index / B: n-index / D: col
  const int q    = lane >> 4;      // quad: k = q*8 + j
  const int jw   = nb * 64 + wv * 16;  // wave's gate base

  // stage this chunk's agg rows (16 nodes x 256 bt, contiguous) into LDS
  {
    const float4* src = (const float4*)(agg_T + (size_t)n0 * 256);
    float4* dst = (float4*)agg_s;
#pragma unroll
    for (int p = 0; p < 4; ++p) dst[tid + p * 256] = src[tid + p * 256];
  }

  // per-lane k-constants: k = q*8 + j
  float wlr[8], gbr[8];
#pragma unroll
  for (int j = 0; j < 8; ++j) {
    wlr[j] = w_lin[q * 8 + j];
    gbr[j] = gat_bias[q * 8 + j];
  }

  floatx4 acc[16];
#pragma unroll
  for (int mt = 0; mt < 16; ++mt)
#pragma unroll
    for (int r = 0; r < 4; ++r) acc[mt][r] = 0.f;

  __syncthreads();

  // B pointer: row = gate jw+i16, col base = n0*32 + q*8
  const float* Wrow = W_ih + (size_t)(jw + i16) * D_ + (size_t)n0 * GH_ + q * 8;

  float4 cb0 = *(const float4*)(Wrow);
  float4 cb1 = *(const float4*)(Wrow + 4);

#pragma unroll 1
  for (int nn = 0; nn < NPC_; ++nn) {
    // prefetch next node's B fragment (nn==15 reloads node 0, discarded)
    const int nnx = (nn + 1) & (NPC_ - 1);
    float4 pb0 = *(const float4*)(Wrow + nnx * GH_);
    float4 pb1 = *(const float4*)(Wrow + nnx * GH_ + 4);

    // pack B hi/lo
    short8 bh, bl;
    {
      U8 Hh, Ll;
      split2(cb0.x, cb0.y, Hh.u[0], Ll.u[0]);
      split2(cb0.z, cb0.w, Hh.u[1], Ll.u[1]);
      split2(cb1.x, cb1.y, Hh.u[2], Ll.u[2]);
      split2(cb1.z, cb1.w, Hh.u[3], Ll.u[3]);
      bh = Hh.s; bl = Ll.s;
    }

#pragma unroll
    for (int mt = 0; mt < 16; ++mt) {
      const float a = agg_s[nn * 256 + mt * 16 + i16];
      U8 Ah, Al;
#pragma unroll
      for (int p = 0; p < 4; ++p) {
        float v0 = fmaf(a, wlr[2 * p],     gbr[2 * p]);
        float v1 = fmaf(a, wlr[2 * p + 1], gbr[2 * p + 1]);
        v0 = fmaxf(v0, 0.f);
        v1 = fmaxf(v1, 0.f);
        split2(v0, v1, Ah.u[p], Al.u[p]);
      }
      acc[mt] = __builtin_amdgcn_mfma_f32_16x16x32_bf16(Ah.s, bh, acc[mt], 0, 0, 0);
      acc[mt] = __builtin_amdgcn_mfma_f32_16x16x32_bf16(Al.s, bh, acc[mt], 0, 0, 0);
      acc[mt] = __builtin_amdgcn_mfma_f32_16x16x32_bf16(Ah.s, bl, acc[mt], 0, 0, 0);
    }
    cb0 = pb0; cb1 = pb1;
  }

  // epilogue: D layout col = lane&15 (=n=gate), row = q*4 + r (=m=bt within tile)
  const int j = jw + i16;
#pragma unroll
  for (int mt = 0; mt < 16; ++mt) {
    const int bt = mt * 16 + q * 4;
    if (use_atomic) {
#pragma unroll
      for (int r = 0; r < 4; ++r) atomicAdd(&pre_gates[(bt + r) * G4_ + j], acc[mt][r]);
    } else {
#pragma unroll
      for (int r = 0; r < 4; ++r)
        partial[((size_t)kc * 256 + (bt + r)) * 256 + j] = acc[mt][r];
    }
  }
}

// ---------------------------------------------------------------------------
// Kernel 2b: reduce partials -> pre_gates.  grid 256 x 256 threads.
// ---------------------------------------------------------------------------
__global__ __launch_bounds__(256) void reduce_kernel(
    const float* __restrict__ partial, float* __restrict__ pre_gates)
{
  const int o = blockIdx.x * 256 + threadIdx.x;
  float s0 = 0.f, s1 = 0.f, s2 = 0.f, s3 = 0.f;
  int kc = 0;
  for (; kc + 4 <= KC_; kc += 4) {
    s0 += partial[(size_t)(kc + 0) * 65536 + o];
    s1 += partial[(size_t)(kc + 1) * 65536 + o];
    s2 += partial[(size_t)(kc + 2) * 65536 + o];
    s3 += partial[(size_t)(kc + 3) * 65536 + o];
  }
  for (; kc < KC_; ++kc) s0 += partial[(size_t)kc * 65536 + o];
  pre_gates[o] = (s0 + s1) + (s2 + s3);
}

// ---------------------------------------------------------------------------
// Kernel 3: LSTM recurrence. One block per batch b.
// ---------------------------------------------------------------------------
__global__ __launch_bounds__(256) void lstm_kernel(
    const float* __restrict__ pre_gates, const float* __restrict__ W_hh,
    const float* __restrict__ b_ih, const float* __restrict__ b_hh,
    float* __restrict__ hT)
{
  const int b   = blockIdx.x;
  const int tid = threadIdx.x;
  __shared__ float Whh_s[G4_ * 65];
  __shared__ float h_s[H_];
  __shared__ float g_s[G4_];

  for (int idx = tid; idx < G4_ * H_; idx += 256) {
    const int j = idx >> 6;
    const int k = idx & 63;
    Whh_s[j * 65 + k] = W_hh[idx];
  }
  if (tid < H_) h_s[tid] = 0.f;
  float c = 0.f;
  const float bias = b_ih[tid] + b_hh[tid];
  __syncthreads();

  for (int t = 0; t < S_; ++t) {
    float g = pre_gates[(size_t)(b * S_ + t) * G4_ + tid] + bias;
#pragma unroll
    for (int k = 0; k < H_; ++k) g = fmaf(Whh_s[tid * 65 + k], h_s[k], g);
    g_s[tid] = g;
    __syncthreads();
    if (tid < H_) {
      const float ig = fsigmoid(g_s[tid]);
      const float fg = fsigmoid(g_s[H_ + tid]);
      const float gg = ftanh_(g_s[2 * H_ + tid]);
      const float og = fsigmoid(g_s[3 * H_ + tid]);
      c = fg * c + ig * gg;
      h_s[tid] = og * ftanh_(c);
    }
    __syncthreads();
  }
  if (tid < H_) hT[b * H_ + tid] = h_s[tid];
}

// ---------------------------------------------------------------------------
// Kernel 4: head. out[b,n] = b_head[n] + sum_h hT[b,h]*W_head[n,h]
// ---------------------------------------------------------------------------
__global__ __launch_bounds__(256) void head_kernel(
    const float* __restrict__ hT, const float* __restrict__ W_head,
    const float* __restrict__ b_head, float* __restrict__ out)
{
  const int o = blockIdx.x * 256 + threadIdx.x;
  if (o >= B_ * N_) return;
  const int b = o / N_;
  const int n = o - b * N_;
  const float4* w4 = (const float4*)(W_head + (size_t)n * H_);
  const float4* h4 = (const float4*)(hT + (size_t)b * H_);
  float acc = b_head[n];
#pragma unroll
  for (int q = 0; q < H_ / 4; ++q) {
    const float4 w = w4[q];
    const float4 h = h4[q];
    acc += w.x * h.x + w.y * h.y + w.z * h.z + w.w * h.w;
  }
  out[o] = acc;
}

// ---------------------------------------------------------------------------
extern "C" void kernel_launch(void* const* d_in, const int* in_sizes, int n_in,
                              void* d_out, int out_size, void* d_ws, size_t ws_size,
                              hipStream_t stream) {
  const float* x        = (const float*)d_in[0];
  const int*   ei       = (const int*)  d_in[1];
  const float* w_lin    = (const float*)d_in[2];
  const float* att_src  = (const float*)d_in[3];
  const float* att_dst  = (const float*)d_in[4];
  const float* gat_bias = (const float*)d_in[5];
  const float* W_ih     = (const float*)d_in[6];
  const float* W_hh     = (const float*)d_in[7];
  const float* b_ih     = (const float*)d_in[8];
  const float* b_hh     = (const float*)d_in[9];
  const float* W_head   = (const float*)d_in[10];
  const float* b_head   = (const float*)d_in[11];
  float* out = (float*)d_out;

  char* ws = (char*)d_ws;
  float* agg_T     = (float*)ws;                          // 2,048,000 B
  float* pre_gates = (float*)(ws + 2048000);              //   262,144 B
  float* hT        = (float*)(ws + 2048000 + 262144);     //     2,048 B
  const size_t PARTIAL_OFF = 2048000 + 262144 + 2048;     // 2,312,192
  float* partial   = (float*)(ws + PARTIAL_OFF);          // 125*65536*4 = 32,768,000 B
  const size_t need = PARTIAL_OFF + (size_t)KC_ * 65536 * sizeof(float);
  const int use_atomic = (ws_size < need) ? 1 : 0;

  gat_agg_kernel<<<dim3(BT_), dim3(256), 0, stream>>>(x, ei, w_lin, att_src, att_dst, agg_T);

  if (use_atomic) {
    hipMemsetAsync(pre_gates, 0, G4_ * BT_ * sizeof(float), stream);
  }

  gate_mfma_kernel<<<dim3(4, KC_), dim3(256), 0, stream>>>(
      W_ih, agg_T, w_lin, gat_bias, partial, pre_gates, use_atomic);

  if (!use_atomic) {
    reduce_kernel<<<dim3(256), dim3(256), 0, stream>>>(partial, pre_gates);
  }

  lstm_kernel<<<dim3(B_), dim3(256), 0, stream>>>(pre_gates, W_hh, b_ih, b_hh, hT);

  head_kernel<<<dim3((B_ * N_ + 255) / 256), dim3(256), 0, stream>>>(hT, W_head, b_head, out);
}

// Round 3
// 249.410 us; speedup vs baseline: 2.3245x; 1.5850x over previous
//
#include <hip/hip_runtime.h>
#include <hip/hip_bf16.h>
#include <cstddef>
#include <cstdint>

#define B_  8
#define S_  32
#define BT_ 256      // B*S
#define N_  2000
#define E_  64000
#define GH_ 32
#define H_  64
#define G4_ 256      // 4*H
#define D_  64000    // N*GH
#define NEG_SLOPE_ 0.2f

#define KC_   125    // K-chunks
#define NPC_  16     // nodes per chunk (125*16 = 2000)

typedef __attribute__((ext_vector_type(8))) short short8;
typedef __attribute__((ext_vector_type(4))) float floatx4;
union U8 { uint32_t u[4]; short8 s; };

__device__ __forceinline__ float fsigmoid(float x) { return 1.0f / (1.0f + __expf(-x)); }
__device__ __forceinline__ float ftanh_(float x)   { return 1.0f - 2.0f / (__expf(2.0f * x) + 1.0f); }

__device__ __forceinline__ void split2(float v0, float v1, uint32_t& hi, uint32_t& lo) {
  uint32_t b0 = __float_as_uint(v0), b1 = __float_as_uint(v1);
  uint32_t h0 = b0 & 0xffff0000u,    h1 = b1 & 0xffff0000u;
  hi = (b0 >> 16) | h1;
  float l0 = v0 - __uint_as_float(h0);
  float l1 = v1 - __uint_as_float(h1);
  lo = (__float_as_uint(l0) >> 16) | (__float_as_uint(l1) & 0xffff0000u);
}

// ---------------------------------------------------------------------------
// GAT pipeline, CSR-gather formulation (round 3 — replaces latency-bound
// scatter/LDS-atomic version that ran at 189 us with 4 waves/CU).
// ---------------------------------------------------------------------------

// G1: degree histogram by dst
__global__ __launch_bounds__(256) void hist_kernel(
    const int* __restrict__ ei, int* __restrict__ deg)
{
  const int i = blockIdx.x * 256 + threadIdx.x;
  if (i < E_) atomicAdd(&deg[ei[E_ + i]], 1);
}

// G2: exclusive scan deg -> rowptr, copy to cursor. One block, 256 threads.
__global__ __launch_bounds__(256) void scan_kernel(
    const int* __restrict__ deg, int* __restrict__ rowptr, int* __restrict__ cursor)
{
  __shared__ int tsum[256];
  const int tid = threadIdx.x;
  int v[8];
  int s = 0;
  const int base = tid * 8;
#pragma unroll
  for (int j = 0; j < 8; ++j) {
    const int idx = base + j;
    const int d = (idx < N_) ? deg[idx] : 0;
    v[j] = s;            // local exclusive prefix
    s += d;
  }
  tsum[tid] = s;
  __syncthreads();
  // Hillis-Steele inclusive scan over 256 thread totals
  for (int off = 1; off < 256; off <<= 1) {
    int t = 0;
    if (tid >= off) t = tsum[tid - off];
    __syncthreads();
    tsum[tid] += t;
    __syncthreads();
  }
  const int ebase = tsum[tid] - s;  // exclusive base for this thread
#pragma unroll
  for (int j = 0; j < 8; ++j) {
    const int idx = base + j;
    if (idx < N_) {
      const int r = ebase + v[j];
      rowptr[idx] = r;
      cursor[idx] = r;
    }
  }
  if (tid == 0) rowptr[N_] = E_;
}

// G3: scatter src indices into CSR buckets
__global__ __launch_bounds__(256) void scatter_kernel(
    const int* __restrict__ ei, int* __restrict__ cursor, int* __restrict__ csr_src)
{
  const int i = blockIdx.x * 256 + threadIdx.x;
  if (i >= E_) return;
  const int s = ei[i];
  const int d = ei[E_ + i];
  const int pos = atomicAdd(&cursor[d], 1);
  csr_src[pos] = s;
}

// G4: transpose x [bt][n] -> xT [n][bt], 32x32 LDS tiles
__global__ __launch_bounds__(256) void transpose_kernel(
    const float* __restrict__ x, float* __restrict__ xT)
{
  __shared__ float tile[32][33];
  const int tx = threadIdx.x & 31;
  const int ty = threadIdx.x >> 5;  // 0..7
  const int n0  = blockIdx.x * 32;
  const int bt0 = blockIdx.y * 32;
#pragma unroll
  for (int r = 0; r < 4; ++r) {
    const int bt = bt0 + ty + r * 8;
    const int nn = n0 + tx;
    if (nn < N_) tile[ty + r * 8][tx] = x[(size_t)bt * N_ + nn];
  }
  __syncthreads();
#pragma unroll
  for (int r = 0; r < 4; ++r) {
    const int n = n0 + ty + r * 8;
    if (n < N_) xT[(size_t)n * BT_ + bt0 + tx] = tile[tx][ty + r * 8];
  }
}

// G5: gather-aggregate. One block per node n; thread = bt.
// agg_T[n][bt] = (sum_in exp(e)*x_src + exp(e_self)*x_n) / (sum exp)
// (softmax max-subtraction is a mathematical no-op; e is bounded ~|4.5|)
__global__ __launch_bounds__(256) void gat_gather_kernel(
    const float* __restrict__ xT, const int* __restrict__ rowptr,
    const int* __restrict__ csr_src,
    const float* __restrict__ w_lin, const float* __restrict__ att_src,
    const float* __restrict__ att_dst, float* __restrict__ agg_T)
{
  __shared__ int srcs[512];
  const int n   = blockIdx.x;
  const int tid = threadIdx.x;

  float c_s = 0.f, c_d = 0.f;
  for (int g = 0; g < GH_; ++g) {
    const float w = w_lin[g];
    c_s += w * att_src[g];
    c_d += w * att_dst[g];
  }

  const int r0 = rowptr[n];
  const int r1 = rowptr[n + 1];
  const int d  = r1 - r0;
  for (int i = tid; i < d && i < 512; i += 256) srcs[i] = csr_src[r0 + i];
  __syncthreads();

  const float xn = xT[(size_t)n * BT_ + tid];
  // self loop
  float e = (c_s + c_d) * xn;
  e = e > 0.f ? e : NEG_SLOPE_ * e;
  float w = __expf(e);
  float num = w * xn;
  float den = w;

  for (int p = 0; p < d; ++p) {
    int s;
    if (p < 512) s = srcs[p]; else s = csr_src[r0 + p];
    const float xs = xT[(size_t)s * BT_ + tid];
    float ee = c_s * xs + c_d * xn;
    ee = ee > 0.f ? ee : NEG_SLOPE_ * ee;
    const float ww = __expf(ee);
    num += ww * xs;
    den += ww;
  }
  agg_T[(size_t)n * BT_ + tid] = num / den;
}

// ---------------------------------------------------------------------------
// Kernel 2: split-bf16 MFMA matmul (unchanged from round 2).
// pre_gates[bt, j] = sum_{n,gh} W_ih[j, n*32+gh] * relu(agg[bt,n]*w_lin[gh]+gat_bias[gh])
// ---------------------------------------------------------------------------
__global__ __launch_bounds__(256) void gate_mfma_kernel(
    const float* __restrict__ W_ih, const float* __restrict__ agg_T,
    const float* __restrict__ w_lin, const float* __restrict__ gat_bias,
    float* __restrict__ partial, float* __restrict__ pre_gates, int use_atomic)
{
  __shared__ float agg_s[NPC_ * 256];

  const int tid  = threadIdx.x;
  const int nb   = blockIdx.x;
  const int kc   = blockIdx.y;
  const int n0   = kc * NPC_;
  const int wv   = tid >> 6;
  const int lane = tid & 63;
  const int i16  = lane & 15;
  const int q    = lane >> 4;
  const int jw   = nb * 64 + wv * 16;

  {
    const float4* src = (const float4*)(agg_T + (size_t)n0 * 256);
    float4* dst = (float4*)agg_s;
#pragma unroll
    for (int p = 0; p < 4; ++p) dst[tid + p * 256] = src[tid + p * 256];
  }

  float wlr[8], gbr[8];
#pragma unroll
  for (int j = 0; j < 8; ++j) {
    wlr[j] = w_lin[q * 8 + j];
    gbr[j] = gat_bias[q * 8 + j];
  }

  floatx4 acc[16];
#pragma unroll
  for (int mt = 0; mt < 16; ++mt)
#pragma unroll
    for (int r = 0; r < 4; ++r) acc[mt][r] = 0.f;

  __syncthreads();

  const float* Wrow = W_ih + (size_t)(jw + i16) * D_ + (size_t)n0 * GH_ + q * 8;

  float4 cb0 = *(const float4*)(Wrow);
  float4 cb1 = *(const float4*)(Wrow + 4);

#pragma unroll 1
  for (int nn = 0; nn < NPC_; ++nn) {
    const int nnx = (nn + 1) & (NPC_ - 1);
    float4 pb0 = *(const float4*)(Wrow + nnx * GH_);
    float4 pb1 = *(const float4*)(Wrow + nnx * GH_ + 4);

    short8 bh, bl;
    {
      U8 Hh, Ll;
      split2(cb0.x, cb0.y, Hh.u[0], Ll.u[0]);
      split2(cb0.z, cb0.w, Hh.u[1], Ll.u[1]);
      split2(cb1.x, cb1.y, Hh.u[2], Ll.u[2]);
      split2(cb1.z, cb1.w, Hh.u[3], Ll.u[3]);
      bh = Hh.s; bl = Ll.s;
    }

#pragma unroll
    for (int mt = 0; mt < 16; ++mt) {
      const float a = agg_s[nn * 256 + mt * 16 + i16];
      U8 Ah, Al;
#pragma unroll
      for (int p = 0; p < 4; ++p) {
        float v0 = fmaf(a, wlr[2 * p],     gbr[2 * p]);
        float v1 = fmaf(a, wlr[2 * p + 1], gbr[2 * p + 1]);
        v0 = fmaxf(v0, 0.f);
        v1 = fmaxf(v1, 0.f);
        split2(v0, v1, Ah.u[p], Al.u[p]);
      }
      acc[mt] = __builtin_amdgcn_mfma_f32_16x16x32_bf16(Ah.s, bh, acc[mt], 0, 0, 0);
      acc[mt] = __builtin_amdgcn_mfma_f32_16x16x32_bf16(Al.s, bh, acc[mt], 0, 0, 0);
      acc[mt] = __builtin_amdgcn_mfma_f32_16x16x32_bf16(Ah.s, bl, acc[mt], 0, 0, 0);
    }
    cb0 = pb0; cb1 = pb1;
  }

  const int j = jw + i16;
#pragma unroll
  for (int mt = 0; mt < 16; ++mt) {
    const int bt = mt * 16 + q * 4;
    if (use_atomic) {
#pragma unroll
      for (int r = 0; r < 4; ++r) atomicAdd(&pre_gates[(bt + r) * G4_ + j], acc[mt][r]);
    } else {
#pragma unroll
      for (int r = 0; r < 4; ++r)
        partial[((size_t)kc * 256 + (bt + r)) * 256 + j] = acc[mt][r];
    }
  }
}

// ---------------------------------------------------------------------------
// Kernel 2b: reduce partials -> pre_gates.
// ---------------------------------------------------------------------------
__global__ __launch_bounds__(256) void reduce_kernel(
    const float* __restrict__ partial, float* __restrict__ pre_gates)
{
  const int o = blockIdx.x * 256 + threadIdx.x;
  float s0 = 0.f, s1 = 0.f, s2 = 0.f, s3 = 0.f;
  int kc = 0;
  for (; kc + 4 <= KC_; kc += 4) {
    s0 += partial[(size_t)(kc + 0) * 65536 + o];
    s1 += partial[(size_t)(kc + 1) * 65536 + o];
    s2 += partial[(size_t)(kc + 2) * 65536 + o];
    s3 += partial[(size_t)(kc + 3) * 65536 + o];
  }
  for (; kc < KC_; ++kc) s0 += partial[(size_t)kc * 65536 + o];
  pre_gates[o] = (s0 + s1) + (s2 + s3);
}

// ---------------------------------------------------------------------------
// Kernel 3: LSTM recurrence. One block per batch b. W_hh row + pre_gates
// cached in registers; 4-way split accumulator shortens the serial FMA chain.
// ---------------------------------------------------------------------------
__global__ __launch_bounds__(256) void lstm_kernel(
    const float* __restrict__ pre_gates, const float* __restrict__ W_hh,
    const float* __restrict__ b_ih, const float* __restrict__ b_hh,
    float* __restrict__ hT)
{
  const int b   = blockIdx.x;
  const int tid = threadIdx.x;
  __shared__ float h_s[H_];
  __shared__ float g_s[G4_];

  float wr[H_];
#pragma unroll
  for (int k = 0; k < H_; ++k) wr[k] = W_hh[(size_t)tid * H_ + k];

  float pg[S_];
#pragma unroll
  for (int t = 0; t < S_; ++t) pg[t] = pre_gates[(size_t)(b * S_ + t) * G4_ + tid];

  const float bias = b_ih[tid] + b_hh[tid];
  if (tid < H_) h_s[tid] = 0.f;
  float c = 0.f;
  __syncthreads();

  for (int t = 0; t < S_; ++t) {
    float g0 = pg[t] + bias, g1 = 0.f, g2 = 0.f, g3 = 0.f;
#pragma unroll
    for (int k = 0; k < H_; k += 4) {
      g0 = fmaf(wr[k + 0], h_s[k + 0], g0);
      g1 = fmaf(wr[k + 1], h_s[k + 1], g1);
      g2 = fmaf(wr[k + 2], h_s[k + 2], g2);
      g3 = fmaf(wr[k + 3], h_s[k + 3], g3);
    }
    g_s[tid] = (g0 + g1) + (g2 + g3);
    __syncthreads();
    if (tid < H_) {
      const float ig = fsigmoid(g_s[tid]);
      const float fg = fsigmoid(g_s[H_ + tid]);
      const float gg = ftanh_(g_s[2 * H_ + tid]);
      const float og = fsigmoid(g_s[3 * H_ + tid]);
      c = fg * c + ig * gg;
      h_s[tid] = og * ftanh_(c);
    }
    __syncthreads();
  }
  if (tid < H_) hT[b * H_ + tid] = h_s[tid];
}

// ---------------------------------------------------------------------------
// Kernel 4: head.
// ---------------------------------------------------------------------------
__global__ __launch_bounds__(256) void head_kernel(
    const float* __restrict__ hT, const float* __restrict__ W_head,
    const float* __restrict__ b_head, float* __restrict__ out)
{
  const int o = blockIdx.x * 256 + threadIdx.x;
  if (o >= B_ * N_) return;
  const int b = o / N_;
  const int n = o - b * N_;
  const float4* w4 = (const float4*)(W_head + (size_t)n * H_);
  const float4* h4 = (const float4*)(hT + (size_t)b * H_);
  float acc = b_head[n];
#pragma unroll
  for (int q = 0; q < H_ / 4; ++q) {
    const float4 w = w4[q];
    const float4 h = h4[q];
    acc += w.x * h.x + w.y * h.y + w.z * h.z + w.w * h.w;
  }
  out[o] = acc;
}

// ---------------------------------------------------------------------------
extern "C" void kernel_launch(void* const* d_in, const int* in_sizes, int n_in,
                              void* d_out, int out_size, void* d_ws, size_t ws_size,
                              hipStream_t stream) {
  const float* x        = (const float*)d_in[0];
  const int*   ei       = (const int*)  d_in[1];
  const float* w_lin    = (const float*)d_in[2];
  const float* att_src  = (const float*)d_in[3];
  const float* att_dst  = (const float*)d_in[4];
  const float* gat_bias = (const float*)d_in[5];
  const float* W_ih     = (const float*)d_in[6];
  const float* W_hh     = (const float*)d_in[7];
  const float* b_ih     = (const float*)d_in[8];
  const float* b_hh     = (const float*)d_in[9];
  const float* W_head   = (const float*)d_in[10];
  const float* b_head   = (const float*)d_in[11];
  float* out = (float*)d_out;

  char* ws = (char*)d_ws;
  float* agg_T     = (float*)(ws + 0);              // 2,048,000
  float* pre_gates = (float*)(ws + 2048000);        //   262,144
  float* hT        = (float*)(ws + 2310144);        //     2,048
  float* xT        = (float*)(ws + 2312192);        // 2,048,000
  int*   deg       = (int*)  (ws + 4360192);        //     8,192
  int*   rowptr    = (int*)  (ws + 4368384);        //     8,192
  int*   cursor    = (int*)  (ws + 4376576);        //     8,192
  int*   csr_src   = (int*)  (ws + 4384768);        //   256,000
  float* partial   = (float*)(ws + 4640768);        // 32,768,000 (optional)
  const size_t need = 4640768 + (size_t)KC_ * 65536 * sizeof(float);
  const int use_atomic = (ws_size < need) ? 1 : 0;

  // --- GAT: CSR build + transpose + gather ---
  hipMemsetAsync(deg, 0, N_ * sizeof(int), stream);
  hist_kernel<<<dim3((E_ + 255) / 256), dim3(256), 0, stream>>>(ei, deg);
  scan_kernel<<<dim3(1), dim3(256), 0, stream>>>(deg, rowptr, cursor);
  scatter_kernel<<<dim3((E_ + 255) / 256), dim3(256), 0, stream>>>(ei, cursor, csr_src);
  transpose_kernel<<<dim3((N_ + 31) / 32, BT_ / 32), dim3(256), 0, stream>>>(x, xT);
  gat_gather_kernel<<<dim3(N_), dim3(256), 0, stream>>>(
      xT, rowptr, csr_src, w_lin, att_src, att_dst, agg_T);

  // --- gate matmul ---
  if (use_atomic) {
    hipMemsetAsync(pre_gates, 0, G4_ * BT_ * sizeof(float), stream);
  }
  gate_mfma_kernel<<<dim3(4, KC_), dim3(256), 0, stream>>>(
      W_ih, agg_T, w_lin, gat_bias, partial, pre_gates, use_atomic);
  if (!use_atomic) {
    reduce_kernel<<<dim3(256), dim3(256), 0, stream>>>(partial, pre_gates);
  }

  // --- LSTM + head ---
  lstm_kernel<<<dim3(B_), dim3(256), 0, stream>>>(pre_gates, W_hh, b_ih, b_hh, hT);
  head_kernel<<<dim3((B_ * N_ + 255) / 256), dim3(256), 0, stream>>>(hT, W_head, b_head, out);
}